// Round 1
// baseline (5743.528 us; speedup 1.0000x reference)
//
#include <hip/hip_runtime.h>
#include <math.h>

#define NPTS 2048
#define DIM 32
#define NPAIR 5
#define NT 6

#if __has_builtin(__builtin_amdgcn_exp2f)
__device__ __forceinline__ float exp2_fast(float x) { return __builtin_amdgcn_exp2f(x); }
#else
__device__ __forceinline__ float exp2_fast(float x) { return exp2f(x); }
#endif
#if __has_builtin(__builtin_amdgcn_logf)
__device__ __forceinline__ float log2_fast(float x) { return __builtin_amdgcn_logf(x); }
#else
__device__ __forceinline__ float log2_fast(float x) { return log2f(x); }
#endif

// Online base-2 LSE update, single exp2 per element (branch-free select).
// mn = max(m,u); if u>m: s = s*2^(m-u) + 1 else s = s + 2^(u-m)
__device__ __forceinline__ void lse_update(float& m, float& s, float u) {
  float mn = fmaxf(m, u);
  float e = exp2_fast(fminf(m, u) - mn);
  bool gt = u > m;
  s = fmaf(s, gt ? e : 1.0f, gt ? 1.0f : e);
  m = mn;
}

// Merge two (m,s) LSE partials (symmetric 2-exp form; rare path).
__device__ __forceinline__ void lse_merge(float& m, float& s, float m2, float s2) {
  float mn = fmaxf(m, m2);
  s = fmaf(s, exp2_fast(m - mn), s2 * exp2_fast(m2 - mn));
  m = mn;
}

__global__ __launch_bounds__(256) void init_kernel(
    const float* __restrict__ x, float* __restrict__ norms,
    float* __restrict__ f, float* __restrict__ g) {
  int idx = blockIdx.x * 256 + threadIdx.x;
  if (idx < NT * NPTS) {
    const float* row = x + (size_t)idx * DIM;
    float d0 = 0.f, d1 = 0.f, d2 = 0.f, d3 = 0.f;
#pragma unroll
    for (int k = 0; k < DIM; k += 4) {
      d0 = fmaf(row[k + 0], row[k + 0], d0);
      d1 = fmaf(row[k + 1], row[k + 1], d1);
      d2 = fmaf(row[k + 2], row[k + 2], d2);
      d3 = fmaf(row[k + 3], row[k + 3], d3);
    }
    norms[idx] = (d0 + d1) + (d2 + d3);
  }
  if (idx < NPAIR * NPTS) { f[idx] = 0.f; g[idx] = 0.f; }
}

// C[p][i][j] = 0.5*(|x_i|^2 + |y_j|^2) - x_i . y_j   (x = timepoint p, y = p+1)
__global__ __launch_bounds__(256) void cmat_kernel(
    const float* __restrict__ x, const float* __restrict__ norms, float* __restrict__ C) {
  int bid = blockIdx.x;
  int p = bid >> 10;
  int ib = (bid >> 5) & 31;
  int jb = bid & 31;
  const float* xr = x + (size_t)p * NPTS * DIM;
  const float* yr = x + (size_t)(p + 1) * NPTS * DIM;
  __shared__ float xs[64][DIM];        // broadcast reads (wave-uniform row)
  __shared__ float ys[64][DIM + 1];    // pad 33: bank = (jloc+k)&31 -> 2-way (free)
  int tid = threadIdx.x;
  for (int r = 0; r < 8; ++r) {
    int e = (r << 8) + tid;            // coalesced staging
    int i = e >> 5, k = e & 31;
    xs[i][k] = xr[(size_t)(ib << 6) * DIM + e];
    ys[i][k] = yr[(size_t)(jb << 6) * DIM + e];
  }
  __syncthreads();
  int jloc = tid & 63, istrip = tid >> 6;
  float nyv = norms[(p + 1) * NPTS + (jb << 6) + jloc];
  for (int ii = 0; ii < 16; ++ii) {
    int i = (istrip << 4) + ii;
    float d0 = 0.f, d1 = 0.f, d2 = 0.f, d3 = 0.f;
#pragma unroll
    for (int k = 0; k < DIM; k += 4) {
      d0 = fmaf(xs[i][k + 0], ys[jloc][k + 0], d0);
      d1 = fmaf(xs[i][k + 1], ys[jloc][k + 1], d1);
      d2 = fmaf(xs[i][k + 2], ys[jloc][k + 2], d2);
      d3 = fmaf(xs[i][k + 3], ys[jloc][k + 3], d3);
    }
    float nxv = norms[p * NPTS + (ib << 6) + i];
    C[((size_t)p * NPTS + (ib << 6) + i) * NPTS + (jb << 6) + jloc] =
        fmaf(0.5f, nxv + nyv, -((d0 + d1) + (d2 + d3)));
  }
}

// g_j = -eps*ln2*LSE2_i[(f_i - C_ij)/(eps*ln2)] + eps*ln(n)
// thread-per-column, 4 i-strips of 512 per block, LDS strip merge.
__global__ __launch_bounds__(256) void g_kernel_c(
    const float* __restrict__ C, const float* __restrict__ f, float* __restrict__ g,
    float kk, float cs, float cb) {
  int bid = blockIdx.x;
  int p = bid >> 5, jb = bid & 31;
  int tid = threadIdx.x;
  int jloc = tid & 63, strip = tid >> 6;
  int j = (jb << 6) + jloc;
  const float* Cp = C + ((size_t)p * NPTS + (size_t)strip * 512) * NPTS + j;
  const float* fp = f + p * NPTS + strip * 512;
  float m0 = -INFINITY, m1 = -INFINITY, m2 = -INFINITY, m3 = -INFINITY;
  float s0 = 0.f, s1 = 0.f, s2 = 0.f, s3 = 0.f;
  for (int ii = 0; ii < 512; ii += 4) {
    float c0 = Cp[(size_t)(ii + 0) * NPTS];
    float c1 = Cp[(size_t)(ii + 1) * NPTS];
    float c2 = Cp[(size_t)(ii + 2) * NPTS];
    float c3 = Cp[(size_t)(ii + 3) * NPTS];
    float u0 = (fp[ii + 0] - c0) * kk;
    float u1 = (fp[ii + 1] - c1) * kk;
    float u2 = (fp[ii + 2] - c2) * kk;
    float u3 = (fp[ii + 3] - c3) * kk;
    lse_update(m0, s0, u0);
    lse_update(m1, s1, u1);
    lse_update(m2, s2, u2);
    lse_update(m3, s3, u3);
  }
  lse_merge(m0, s0, m1, s1);
  lse_merge(m2, s2, m3, s3);
  lse_merge(m0, s0, m2, s2);
  __shared__ float lm[4][64], lsum[4][64];
  lm[strip][jloc] = m0; lsum[strip][jloc] = s0;
  __syncthreads();
  if (tid < 64) {
    float M = lm[0][tid], S = lsum[0][tid];
    lse_merge(M, S, lm[1][tid], lsum[1][tid]);
    lse_merge(M, S, lm[2][tid], lsum[2][tid]);
    lse_merge(M, S, lm[3][tid], lsum[3][tid]);
    g[p * NPTS + (jb << 6) + tid] = fmaf(cs, M + log2_fast(S), cb);
  }
}

// f_i = -eps*ln2*LSE2_j[(g_j - C_ij)/(eps*ln2)] + eps*ln(n)
// wave-per-row, float4 loads, shuffle-xor butterfly merge.
__global__ __launch_bounds__(256) void f_kernel_c(
    const float* __restrict__ C, const float* __restrict__ g, float* __restrict__ f,
    float kk, float cs, float cb) {
  int bid = blockIdx.x;
  int p = bid >> 5, rb = bid & 31;
  int tid = threadIdx.x;
  int lane = tid & 63, w = tid >> 6;
  const float4* g4 = (const float4*)(g + p * NPTS);
  for (int rr = 0; rr < 16; ++rr) {
    int i = (rb << 6) + (w << 4) + rr;
    const float4* C4 = (const float4*)(C + ((size_t)p * NPTS + i) * NPTS);
    float m0 = -INFINITY, m1 = -INFINITY, m2 = -INFINITY, m3 = -INFINITY;
    float s0 = 0.f, s1 = 0.f, s2 = 0.f, s3 = 0.f;
    for (int jb2 = 0; jb2 < 8; ++jb2) {
      int idx4 = (jb2 << 6) + lane;
      float4 c4 = C4[idx4];
      float4 gg = g4[idx4];
      lse_update(m0, s0, (gg.x - c4.x) * kk);
      lse_update(m1, s1, (gg.y - c4.y) * kk);
      lse_update(m2, s2, (gg.z - c4.z) * kk);
      lse_update(m3, s3, (gg.w - c4.w) * kk);
    }
    lse_merge(m0, s0, m1, s1);
    lse_merge(m2, s2, m3, s3);
    lse_merge(m0, s0, m2, s2);
    for (int off = 32; off > 0; off >>= 1) {
      float mm = __shfl_xor(m0, off, 64);
      float ss = __shfl_xor(s0, off, 64);
      lse_merge(m0, s0, mm, ss);
    }
    if (lane == 0) f[p * NPTS + i] = fmaf(cs, m0 + log2_fast(s0), cb);
  }
}

// ---- fallback path (workspace too small for C): recompute C inline ----
__global__ __launch_bounds__(256) void g_kernel_noc(
    const float* __restrict__ x, const float* __restrict__ norms,
    const float* __restrict__ f, float* __restrict__ g,
    float kk, float cs, float cb) {
  int bid = blockIdx.x;
  int p = bid >> 5, jb = bid & 31;
  int tid = threadIdx.x;
  int jloc = tid & 63, strip = tid >> 6;
  int j = (jb << 6) + jloc;
  const float* yrow = x + ((size_t)(p + 1) * NPTS + j) * DIM;
  float yv[DIM];
#pragma unroll
  for (int k = 0; k < DIM; ++k) yv[k] = yrow[k];
  float nyv = norms[(p + 1) * NPTS + j];
  const float* xp = x + ((size_t)p * NPTS + (size_t)strip * 512) * DIM;
  const float* nxp = norms + p * NPTS + strip * 512;
  const float* fp = f + p * NPTS + strip * 512;
  float m = -INFINITY, s = 0.f;
  for (int ii = 0; ii < 512; ++ii) {
    const float* xr = xp + (size_t)ii * DIM;
    float d0 = 0.f, d1 = 0.f, d2 = 0.f, d3 = 0.f;
#pragma unroll
    for (int k = 0; k < DIM; k += 4) {
      d0 = fmaf(xr[k + 0], yv[k + 0], d0);
      d1 = fmaf(xr[k + 1], yv[k + 1], d1);
      d2 = fmaf(xr[k + 2], yv[k + 2], d2);
      d3 = fmaf(xr[k + 3], yv[k + 3], d3);
    }
    float c = fmaf(0.5f, nxp[ii] + nyv, -((d0 + d1) + (d2 + d3)));
    lse_update(m, s, (fp[ii] - c) * kk);
  }
  __shared__ float lm[4][64], lsum[4][64];
  lm[strip][jloc] = m; lsum[strip][jloc] = s;
  __syncthreads();
  if (tid < 64) {
    float M = lm[0][tid], S = lsum[0][tid];
    lse_merge(M, S, lm[1][tid], lsum[1][tid]);
    lse_merge(M, S, lm[2][tid], lsum[2][tid]);
    lse_merge(M, S, lm[3][tid], lsum[3][tid]);
    g[p * NPTS + (jb << 6) + tid] = fmaf(cs, M + log2_fast(S), cb);
  }
}

__global__ __launch_bounds__(256) void f_kernel_noc(
    const float* __restrict__ x, const float* __restrict__ norms,
    const float* __restrict__ g, float* __restrict__ f,
    float kk, float cs, float cb) {
  int bid = blockIdx.x;
  int p = bid >> 5, rb = bid & 31;
  int tid = threadIdx.x;
  int lane = tid & 63, w = tid >> 6;
  const float* yp = x + (size_t)(p + 1) * NPTS * DIM;
  const float* nyp = norms + (p + 1) * NPTS;
  const float* gp = g + p * NPTS;
  for (int rr = 0; rr < 16; ++rr) {
    int i = (rb << 6) + (w << 4) + rr;
    const float* xr = x + ((size_t)p * NPTS + i) * DIM;
    float xv[DIM];
#pragma unroll
    for (int k = 0; k < DIM; ++k) xv[k] = xr[k];
    float nxv = norms[p * NPTS + i];
    float m = -INFINITY, s = 0.f;
    for (int jb2 = 0; jb2 < 32; ++jb2) {
      int j = (jb2 << 6) + lane;
      const float* yr = yp + (size_t)j * DIM;
      float d0 = 0.f, d1 = 0.f, d2 = 0.f, d3 = 0.f;
#pragma unroll
      for (int k = 0; k < DIM; k += 4) {
        d0 = fmaf(xv[k + 0], yr[k + 0], d0);
        d1 = fmaf(xv[k + 1], yr[k + 1], d1);
        d2 = fmaf(xv[k + 2], yr[k + 2], d2);
        d3 = fmaf(xv[k + 3], yr[k + 3], d3);
      }
      float c = fmaf(0.5f, nxv + nyp[j], -((d0 + d1) + (d2 + d3)));
      lse_update(m, s, (gp[j] - c) * kk);
    }
    for (int off = 32; off > 0; off >>= 1) {
      float mm = __shfl_xor(m, off, 64);
      float ss = __shfl_xor(s, off, 64);
      lse_merge(m, s, mm, ss);
    }
    if (lane == 0) f[p * NPTS + i] = fmaf(cs, m + log2_fast(s), cb);
  }
}

__global__ __launch_bounds__(256) void out_kernel(
    const float* __restrict__ f, const float* __restrict__ g, float* __restrict__ out) {
  int p = blockIdx.x;
  int tid = threadIdx.x;
  float s = 0.f;
  for (int r = tid; r < NPTS; r += 256) s += f[p * NPTS + r] + g[p * NPTS + r];
  __shared__ float red[256];
  red[tid] = s;
  __syncthreads();
  for (int h = 128; h > 0; h >>= 1) {
    if (tid < h) red[tid] += red[tid + h];
    __syncthreads();
  }
  if (tid == 0) atomicAdd(out, red[0] * (0.05f / (float)NPTS));
}

extern "C" void kernel_launch(void* const* d_in, const int* in_sizes, int n_in,
                              void* d_out, int out_size, void* d_ws, size_t ws_size,
                              hipStream_t stream) {
  const float* x = (const float*)d_in[0];
  float* out = (float*)d_out;
  float* f = (float*)d_ws;
  float* g = f + NPAIR * NPTS;
  float* norms = g + NPAIR * NPTS;
  size_t head = (size_t)(NPAIR * 2 + NT) * NPTS * sizeof(float);
  size_t coff = (head + 255) & ~(size_t)255;
  size_t cbytes = (size_t)NPAIR * NPTS * NPTS * sizeof(float);
  int have_c = (ws_size >= coff + cbytes) ? 1 : 0;
  float* C = (float*)((char*)d_ws + coff);

  hipMemsetAsync(d_out, 0, sizeof(float), stream);
  init_kernel<<<(NT * NPTS + 255) / 256, 256, 0, stream>>>(x, norms, f, g);
  if (have_c) cmat_kernel<<<NPAIR * 1024, 256, 0, stream>>>(x, norms, C);

  const double LN2 = 0.6931471805599453;
  const double LOGN = 7.624618986159398;  // ln(2048)
  for (int t = 0; t < 80; ++t) {
    double eps = 100.0 * pow(0.95, 2.0 * (double)t);
    if (eps < 0.05) eps = 0.05;
    float kk = (float)(1.0 / (eps * LN2));   // 1/(eps*ln2): exponent -> base-2
    float cs = (float)(-eps * LN2);          // -eps*ln2
    float cb = (float)(eps * LOGN);          // +eps*ln(n)  (uniform weights)
    if (have_c) {
      g_kernel_c<<<NPAIR * 32, 256, 0, stream>>>(C, f, g, kk, cs, cb);
      f_kernel_c<<<NPAIR * 32, 256, 0, stream>>>(C, g, f, kk, cs, cb);
    } else {
      g_kernel_noc<<<NPAIR * 32, 256, 0, stream>>>(x, norms, f, g, kk, cs, cb);
      f_kernel_noc<<<NPAIR * 32, 256, 0, stream>>>(x, norms, g, f, kk, cs, cb);
    }
  }
  out_kernel<<<NPAIR, 256, 0, stream>>>(f, g, out);
}